// Round 5
// baseline (324.280 us; speedup 1.0000x reference)
//
#include <hip/hip_runtime.h>
#include <math.h>
#include <stdint.h>

// B=4, C=256, H=W=64 -> HW=4096, C4=64
#define HWN 4096
#define CIN 256
#define CQ 64
#define LOG2E 1.44269504f
#define C2OFF 56.0f    // fixed softmax offset (exp2 domain); P kept in bf16
                       // (fp32 exponent range) -> tail-query underflow impossible

typedef __attribute__((ext_vector_type(8))) _Float16 f16x8;
typedef __attribute__((ext_vector_type(4))) _Float16 f16x4;
typedef __attribute__((ext_vector_type(8))) short    bf16x8;
typedef __attribute__((ext_vector_type(4))) short    bf16x4;
typedef __attribute__((ext_vector_type(4))) float    f32x4;

__device__ __forceinline__ short f2bf(float f) {
  union { float f; uint32_t u; } c; c.f = f;
  uint32_t r = (c.u + 0x7FFFu + ((c.u >> 16) & 1u)) >> 16;   // RNE
  return (short)(uint16_t)r;
}

// ---------------------------------------------------------------- prep ----
__global__ __launch_bounds__(256) void prep_kernel(
    const float* __restrict__ Wqk, const float* __restrict__ Wkl,
    const float* __restrict__ Wkf, const float* __restrict__ Wv,
    const float* __restrict__ Wfire, const float* __restrict__ bfire,
    const float* __restrict__ gamma, const float* __restrict__ beta,
    const float* __restrict__ mean,  const float* __restrict__ var,
    _Float16* __restrict__ wqk_h, _Float16* __restrict__ wkl_h,
    _Float16* __restrict__ wkf_h, _Float16* __restrict__ wv_h,
    _Float16* __restrict__ wf_h, float* __restrict__ scale, float* __restrict__ shift) {
  int gid = blockIdx.x * 256 + threadIdx.x;
  if (gid < CQ * CIN) {
    wqk_h[gid] = (_Float16)(Wqk[gid] * LOG2E);
    wkl_h[gid] = (_Float16)Wkl[gid];
    wkf_h[gid] = (_Float16)Wkf[gid];
    wv_h[gid]  = (_Float16)Wv[gid];
  }
  if (gid < CIN * 128) wf_h[gid] = (_Float16)Wfire[gid];
  if (gid < CIN) {
    float inv = gamma[gid] / sqrtf(var[gid] + 1e-5f);
    scale[gid] = inv;
    shift[gid] = (bfire[gid] - mean[gid]) * inv + beta[gid];
  }
}

// ---------------------------------------------------------------- proj ----
// (unchanged from R4) 3 passes: cur->q(f16,[c][hw])+v(bf16,[c][hw]);
// last->kl(f16,[hw][c]); fut->kf(f16,[hw][c]). Grid 768.
__global__ __launch_bounds__(256) void proj_kernel(
    const float* __restrict__ cur, const float* __restrict__ last, const float* __restrict__ fut,
    const _Float16* __restrict__ wqk, const float* __restrict__ bqk,
    const _Float16* __restrict__ wkl, const float* __restrict__ bkl,
    const _Float16* __restrict__ wkf, const float* __restrict__ bkf,
    const _Float16* __restrict__ wv,  const float* __restrict__ bv,
    _Float16* __restrict__ q_out, _Float16* __restrict__ kl_out,
    _Float16* __restrict__ kf_out, short* __restrict__ v_out) {
  const int tid  = threadIdx.x;
  const int w    = tid >> 6;
  const int lane = tid & 63;
  const int quad = lane >> 4;
  const int l15  = lane & 15;
  const int pass = blockIdx.x >> 8;
  const int bb   = blockIdx.x & 255;
  const int b    = bb >> 6;
  const int hwt  = (bb & 63) << 6;
  const int hw   = hwt + w * 16 + l15;

  if (pass == 0) {
    f32x4 aq[4] = {}; f32x4 av[4] = {};
    for (int k0 = 0; k0 < CIN; k0 += 32) {
      f16x8 bh;
      for (int j = 0; j < 8; ++j)
        bh[j] = (_Float16)cur[(b * CIN + k0 + quad * 8 + j) * HWN + hw];
      for (int mt = 0; mt < 4; ++mt) {
        f16x8 wa = *(const f16x8*)(wqk + (mt * 16 + l15) * CIN + k0 + quad * 8);
        aq[mt] = __builtin_amdgcn_mfma_f32_16x16x32_f16(wa, bh, aq[mt], 0, 0, 0);
        f16x8 wb = *(const f16x8*)(wv + (mt * 16 + l15) * CIN + k0 + quad * 8);
        av[mt] = __builtin_amdgcn_mfma_f32_16x16x32_f16(wb, bh, av[mt], 0, 0, 0);
      }
    }
    for (int mt = 0; mt < 4; ++mt)
      for (int r = 0; r < 4; ++r) {
        int oc = mt * 16 + quad * 4 + r;
        q_out[(b * CQ + oc) * HWN + hw] = (_Float16)(aq[mt][r] + bqk[oc] * LOG2E);
        v_out[(b * CQ + oc) * HWN + hw] = f2bf(av[mt][r] + bv[oc]);
      }
  } else {
    const float* X = (pass == 1) ? last : fut;
    const _Float16* W = (pass == 1) ? wkl : wkf;
    const float* BI = (pass == 1) ? bkl : bkf;
    _Float16* OUT = (pass == 1) ? kl_out : kf_out;
    f32x4 a[4] = {};
    for (int k0 = 0; k0 < CIN; k0 += 32) {
      f16x8 bh;
      for (int j = 0; j < 8; ++j)
        bh[j] = (_Float16)X[(b * CIN + k0 + quad * 8 + j) * HWN + hw];
      for (int mt = 0; mt < 4; ++mt) {
        f16x8 wa = *(const f16x8*)(W + (mt * 16 + l15) * CIN + k0 + quad * 8);
        a[mt] = __builtin_amdgcn_mfma_f32_16x16x32_f16(wa, bh, a[mt], 0, 0, 0);
      }
    }
    for (int mt = 0; mt < 4; ++mt)
      for (int r = 0; r < 4; ++r) {
        int oc = mt * 16 + quad * 4 + r;
        OUT[(b * HWN + hw) * CQ + oc] = (_Float16)(a[mt][r] + BI[oc]);
      }
  }
}

// ---------------------------------------------------------------- attn ----
// Register-resident P: S computed TRANSPOSED (A=K, B=Q), so the S^T C-layout
// (row = quad*4+r = key) is exactly the A-layout of the K=16 PV MFMA
// (k = quad*4+j). No LDS, no barriers in the main loop. P/V bf16, QK f16.
// Block = 32 queries x (pair,b); wave = one 1024-key quarter; grid 1024.
// End: 4-way cross-wave combine through LDS (one barrier total).
__global__ __launch_bounds__(256, 2) void attn_kernel(
    const _Float16* __restrict__ qbuf, const _Float16* __restrict__ klbuf,
    const _Float16* __restrict__ kfbuf, const short* __restrict__ vbuf,
    _Float16* __restrict__ fused) {
  const int tid  = threadIdx.x;
  const int kh   = tid >> 6;                // key quarter
  const int lane = tid & 63;
  const int quad = lane >> 4;
  const int l15  = lane & 15;
  const int bx   = blockIdx.x;
  const int pair = bx & 1;
  const int b    = (bx >> 1) & 3;
  const int qt   = (bx >> 3) << 5;          // 32 queries per block

  const _Float16* K = (pair ? kfbuf : klbuf) + b * HWN * CQ;  // [key][c] f16
  const short*    V = vbuf + b * CQ * HWN;                     // [c][key] bf16

  __shared__ float Cbuf[3][64][34];   // waves 1..3 partials: 32 O + 2 psum

  // B-operand Q frags: B[k=c (quad*8+j)][n=query (l15)], per i (16q) and kk.
  f16x8 qfrag[2][2];
  for (int i = 0; i < 2; ++i)
    for (int kk = 0; kk < 2; ++kk)
      for (int j = 0; j < 8; ++j)
        qfrag[i][kk][j] = qbuf[(b * CQ + kk * 32 + quad * 8 + j) * HWN + qt + i * 16 + l15];

  f32x4 Oacc[2][4] = {};     // [i][ct]: row=q(quad*4+r), col=c4(ct*16+l15)
  float psum[2] = {0.f, 0.f};  // per-lane partial row-sum, q = l15

  const int kt0 = kh << 10, ktend = kt0 + 1024;

  auto loadK = [&](f16x8 (&dst)[4][2], int KT) {
    // A[m=key (l15)][k=c (quad*8+j)] from K[key][c]: 16B contiguous.
    for (int nt = 0; nt < 4; ++nt)
      for (int kk = 0; kk < 2; ++kk)
        dst[nt][kk] = *(const f16x8*)(K + (KT + nt * 16 + l15) * CQ + kk * 32 + quad * 8);
  };

  auto body = [&](f16x8 (&KF)[4][2], int KT) {
    // V B-frags for K=16 PV: B[k=key (quad*4+j)][n=c4 (l15)]: 8B contiguous.
    bf16x4 vf[4][4];
    for (int nt = 0; nt < 4; ++nt)
      for (int ct = 0; ct < 4; ++ct)
        vf[nt][ct] = *(const bf16x4*)(V + (ct * 16 + l15) * HWN + KT + nt * 16 + quad * 4);
    f32x4 ST[2][4] = {};
    for (int i = 0; i < 2; ++i)
      for (int nt = 0; nt < 4; ++nt)
        for (int kk = 0; kk < 2; ++kk)
          ST[i][nt] = __builtin_amdgcn_mfma_f32_16x16x32_f16(KF[nt][kk], qfrag[i][kk], ST[i][nt], 0, 0, 0);
    for (int i = 0; i < 2; ++i)
      for (int nt = 0; nt < 4; ++nt) {
        bf16x4 pf;
        for (int r = 0; r < 4; ++r) {
          float p = __builtin_amdgcn_exp2f(ST[i][nt][r] - C2OFF);
          psum[i] += p;
          pf[r] = f2bf(p);
        }
        for (int ct = 0; ct < 4; ++ct)
          Oacc[i][ct] = __builtin_amdgcn_mfma_f32_16x16x16bf16_1k(pf, vf[nt][ct], Oacc[i][ct], 0, 0, 0);
      }
  };

  f16x8 kA[4][2], kB[4][2];
  loadK(kA, kt0);
  for (int kt = kt0; kt < ktend; kt += 128) {
    loadK(kB, kt + 64);
    body(kA, kt);
    int ktn = (kt + 128 < ktend) ? kt + 128 : kt0;   // last prefetch: benign wrap
    loadK(kA, ktn);
    body(kB, kt + 64);
  }

  // psum currently per-lane over (quad's keys); reduce across the 4 quads
  // (lanes l15, l15+16, +32, +48) -> every lane holds row-sum for q=l15.
  for (int i = 0; i < 2; ++i) {
    psum[i] += __shfl_xor(psum[i], 16);
    psum[i] += __shfl_xor(psum[i], 32);
  }

  if (kh > 0) {
    float* dst = Cbuf[kh - 1][lane];
    for (int i = 0; i < 2; ++i)
      for (int ct = 0; ct < 4; ++ct)
        for (int r = 0; r < 4; ++r) dst[i * 16 + ct * 4 + r] = Oacc[i][ct][r];
    dst[32] = psum[0]; dst[33] = psum[1];
  }
  __syncthreads();
  if (kh == 0) {
    float ltot[2] = {psum[0], psum[1]};
    for (int k = 0; k < 3; ++k) {
      const float* src = Cbuf[k][lane];
      for (int i = 0; i < 2; ++i)
        for (int ct = 0; ct < 4; ++ct)
          for (int r = 0; r < 4; ++r) Oacc[i][ct][r] += src[i * 16 + ct * 4 + r];
      ltot[0] += src[32]; ltot[1] += src[33];
    }
    for (int i = 0; i < 2; ++i)
      for (int r = 0; r < 4; ++r) {
        // ltot lives at q=l15; Oacc rows are q=quad*4+r -> broadcast.
        float lt = __shfl(ltot[i], quad * 4 + r);
        float invl = __builtin_amdgcn_rcpf(lt);
        int qi = qt + i * 16 + quad * 4 + r;
        for (int ct = 0; ct < 4; ++ct)
          fused[(b * HWN + qi) * 128 + pair * 64 + ct * 16 + l15] =
              (_Float16)(Oacc[i][ct][r] * invl);
      }
  }
}

// ---------------------------------------------------------------- fire ----
// (unchanged from R4) Wave = 16 hw x 64 oc; grid 1024.
__global__ __launch_bounds__(256) void fire_kernel(
    const _Float16* __restrict__ fused, const _Float16* __restrict__ wf,
    const float* __restrict__ scale, const float* __restrict__ shift,
    const float* __restrict__ cur, float* __restrict__ out) {
  const int tid  = threadIdx.x;
  const int w    = tid >> 6;
  const int lane = tid & 63;
  const int quad = lane >> 4;
  const int l15  = lane & 15;
  const int g    = blockIdx.x & 3;
  const int bb   = blockIdx.x >> 2;
  const int b    = bb >> 6;
  const int hwt  = (bb & 63) << 6;
  const int hwb  = hwt + w * 16;

  f16x8 bfr[4];
  for (int k0 = 0; k0 < 4; ++k0)
    bfr[k0] = *(const f16x8*)(fused + (b * HWN + hwb + l15) * 128 + k0 * 32 + quad * 8);

  f32x4 acc[4] = {};
  for (int k0 = 0; k0 < 4; ++k0)
    for (int mt = 0; mt < 4; ++mt) {
      f16x8 af = *(const f16x8*)(wf + (g * 64 + mt * 16 + l15) * 128 + k0 * 32 + quad * 8);
      acc[mt] = __builtin_amdgcn_mfma_f32_16x16x32_f16(af, bfr[k0], acc[mt], 0, 0, 0);
    }

  for (int mt = 0; mt < 4; ++mt)
    for (int r = 0; r < 4; ++r) {
      int oc = g * 64 + mt * 16 + quad * 4 + r;
      int idx = (b * CIN + oc) * HWN + hwb + l15;
      float y = cur[idx] + acc[mt][r] * scale[oc] + shift[oc];
      out[idx] = fmaxf(y, 0.f);
    }
}

// -------------------------------------------------------------- launch ----
extern "C" void kernel_launch(void* const* d_in, const int* in_sizes, int n_in,
                              void* d_out, int out_size, void* d_ws, size_t ws_size,
                              hipStream_t stream) {
  const float* last  = (const float*)d_in[0];
  const float* cur   = (const float*)d_in[1];
  const float* fut   = (const float*)d_in[2];
  const float* Wqk   = (const float*)d_in[3];
  const float* bqk   = (const float*)d_in[4];
  const float* Wkl   = (const float*)d_in[5];
  const float* bkl   = (const float*)d_in[6];
  const float* Wkf   = (const float*)d_in[7];
  const float* bkf   = (const float*)d_in[8];
  const float* Wv    = (const float*)d_in[9];
  const float* bv    = (const float*)d_in[10];
  const float* Wfire = (const float*)d_in[11];
  const float* bfire = (const float*)d_in[12];
  const float* gamma = (const float*)d_in[13];
  const float* beta  = (const float*)d_in[14];
  const float* mean  = (const float*)d_in[15];
  const float* var   = (const float*)d_in[16];

  char* ws = (char*)d_ws;
  _Float16* qb     = (_Float16*)(ws);                    // [4][64][4096]  2 MB
  _Float16* klb    = (_Float16*)(ws + (2u << 20));       // [4][4096][64]  2 MB
  _Float16* kfb    = (_Float16*)(ws + (4u << 20));       // [4][4096][64]  2 MB
  short*    vb     = (short*)   (ws + (6u << 20));       // [4][64][4096]  2 MB bf16
  _Float16* fusedb = (_Float16*)(ws + (8u << 20));       // [4][4096][128] 4 MB
  char* wsm = ws + (12u << 20);
  _Float16* wqk_h = (_Float16*)(wsm);
  _Float16* wkl_h = (_Float16*)(wsm + (32u << 10));
  _Float16* wkf_h = (_Float16*)(wsm + (64u << 10));
  _Float16* wv_h  = (_Float16*)(wsm + (96u << 10));
  _Float16* wf_h  = (_Float16*)(wsm + (128u << 10));
  float*    scale = (float*)   (wsm + (192u << 10));
  float*    shift = (float*)   (wsm + (193u << 10));
  float*    out   = (float*)d_out;

  prep_kernel<<<128, 256, 0, stream>>>(Wqk, Wkl, Wkf, Wv, Wfire, bfire,
                                       gamma, beta, mean, var,
                                       wqk_h, wkl_h, wkf_h, wv_h, wf_h, scale, shift);
  proj_kernel<<<768, 256, 0, stream>>>(cur, last, fut, wqk_h, bqk, wkl_h, bkl,
                                       wkf_h, bkf, wv_h, bv, qb, klb, kfb, vb);
  attn_kernel<<<1024, 256, 0, stream>>>(qb, klb, kfb, vb, fusedb);
  fire_kernel<<<1024, 256, 0, stream>>>(fusedb, wf_h, scale, shift, cur, out);
}

// Round 6
// 264.737 us; speedup vs baseline: 1.2249x; 1.2249x over previous
//
#include <hip/hip_runtime.h>
#include <math.h>
#include <stdint.h>

// B=4, C=256, H=W=64 -> HW=4096, C4=64
#define HWN 4096
#define CIN 256
#define CQ 64
#define LOG2E 1.44269504f
#define C2OFF 56.0f    // fixed softmax offset (exp2 domain); P kept in bf16
                       // (fp32 exponent range) -> tail-query underflow impossible

typedef __attribute__((ext_vector_type(8))) _Float16 f16x8;
typedef __attribute__((ext_vector_type(8))) short    bf16x8;
typedef __attribute__((ext_vector_type(4))) short    bf16x4;
typedef __attribute__((ext_vector_type(4))) float    f32x4;

__device__ __forceinline__ short f2bf(float f) {
  union { float f; uint32_t u; } c; c.f = f;
  uint32_t r = (c.u + 0x7FFFu + ((c.u >> 16) & 1u)) >> 16;   // RNE
  return (short)(uint16_t)r;
}

// ---------------------------------------------------------------- prep ----
__global__ __launch_bounds__(256) void prep_kernel(
    const float* __restrict__ Wqk, const float* __restrict__ Wkl,
    const float* __restrict__ Wkf, const float* __restrict__ Wv,
    const float* __restrict__ Wfire, const float* __restrict__ bfire,
    const float* __restrict__ gamma, const float* __restrict__ beta,
    const float* __restrict__ mean,  const float* __restrict__ var,
    _Float16* __restrict__ wqk_h, _Float16* __restrict__ wkl_h,
    _Float16* __restrict__ wkf_h, _Float16* __restrict__ wv_h,
    _Float16* __restrict__ wf_h, float* __restrict__ scale, float* __restrict__ shift) {
  int gid = blockIdx.x * 256 + threadIdx.x;
  if (gid < CQ * CIN) {
    wqk_h[gid] = (_Float16)(Wqk[gid] * LOG2E);
    wkl_h[gid] = (_Float16)Wkl[gid];
    wkf_h[gid] = (_Float16)Wkf[gid];
    wv_h[gid]  = (_Float16)Wv[gid];
  }
  if (gid < CIN * 128) wf_h[gid] = (_Float16)Wfire[gid];
  if (gid < CIN) {
    float inv = gamma[gid] / sqrtf(var[gid] + 1e-5f);
    scale[gid] = inv;
    shift[gid] = (bfire[gid] - mean[gid]) * inv + beta[gid];
  }
}

// ---------------------------------------------------------------- proj ----
// 3 passes (block-ranges): cur->q(f16,[c][hw])+v(bf16,[c][hw]);
// last->kl(f16,[hw][c]); fut->kf(f16,[hw][c]). X loads double-buffered.
__global__ __launch_bounds__(256) void proj_kernel(
    const float* __restrict__ cur, const float* __restrict__ last, const float* __restrict__ fut,
    const _Float16* __restrict__ wqk, const float* __restrict__ bqk,
    const _Float16* __restrict__ wkl, const float* __restrict__ bkl,
    const _Float16* __restrict__ wkf, const float* __restrict__ bkf,
    const _Float16* __restrict__ wv,  const float* __restrict__ bv,
    _Float16* __restrict__ q_out, _Float16* __restrict__ kl_out,
    _Float16* __restrict__ kf_out, short* __restrict__ v_out) {
  const int tid  = threadIdx.x;
  const int w    = tid >> 6;
  const int lane = tid & 63;
  const int quad = lane >> 4;
  const int l15  = lane & 15;
  const int pass = blockIdx.x >> 8;
  const int bb   = blockIdx.x & 255;
  const int b    = bb >> 6;
  const int hwt  = (bb & 63) << 6;
  const int hw   = hwt + w * 16 + l15;

  const float* X = (pass == 0) ? cur : ((pass == 1) ? last : fut);
  const float* xp = X + (size_t)b * CIN * HWN + hw;

  float xbuf[2][8];
#pragma unroll
  for (int j = 0; j < 8; ++j) xbuf[0][j] = xp[(quad * 8 + j) * HWN];

  if (pass == 0) {
    f32x4 aq[4] = {}; f32x4 av[4] = {};
#pragma unroll
    for (int k0 = 0; k0 < CIN; k0 += 32) {
      int pi = (k0 >> 5) & 1;
      if (k0 + 32 < CIN)
#pragma unroll
        for (int j = 0; j < 8; ++j)
          xbuf[pi ^ 1][j] = xp[(k0 + 32 + quad * 8 + j) * HWN];
      f16x8 bh;
#pragma unroll
      for (int j = 0; j < 8; ++j) bh[j] = (_Float16)xbuf[pi][j];
#pragma unroll
      for (int mt = 0; mt < 4; ++mt) {
        f16x8 wa = *(const f16x8*)(wqk + (mt * 16 + l15) * CIN + k0 + quad * 8);
        aq[mt] = __builtin_amdgcn_mfma_f32_16x16x32_f16(wa, bh, aq[mt], 0, 0, 0);
        f16x8 wb = *(const f16x8*)(wv + (mt * 16 + l15) * CIN + k0 + quad * 8);
        av[mt] = __builtin_amdgcn_mfma_f32_16x16x32_f16(wb, bh, av[mt], 0, 0, 0);
      }
    }
#pragma unroll
    for (int mt = 0; mt < 4; ++mt)
#pragma unroll
      for (int r = 0; r < 4; ++r) {
        int oc = mt * 16 + quad * 4 + r;
        q_out[(b * CQ + oc) * HWN + hw] = (_Float16)(aq[mt][r] + bqk[oc] * LOG2E);
        v_out[(b * CQ + oc) * HWN + hw] = f2bf(av[mt][r] + bv[oc]);
      }
  } else {
    const _Float16* W = (pass == 1) ? wkl : wkf;
    const float* BI = (pass == 1) ? bkl : bkf;
    _Float16* OUT = (pass == 1) ? kl_out : kf_out;
    f32x4 a[4] = {};
#pragma unroll
    for (int k0 = 0; k0 < CIN; k0 += 32) {
      int pi = (k0 >> 5) & 1;
      if (k0 + 32 < CIN)
#pragma unroll
        for (int j = 0; j < 8; ++j)
          xbuf[pi ^ 1][j] = xp[(k0 + 32 + quad * 8 + j) * HWN];
      f16x8 bh;
#pragma unroll
      for (int j = 0; j < 8; ++j) bh[j] = (_Float16)xbuf[pi][j];
#pragma unroll
      for (int mt = 0; mt < 4; ++mt) {
        f16x8 wa = *(const f16x8*)(W + (mt * 16 + l15) * CIN + k0 + quad * 8);
        a[mt] = __builtin_amdgcn_mfma_f32_16x16x32_f16(wa, bh, a[mt], 0, 0, 0);
      }
    }
#pragma unroll
    for (int mt = 0; mt < 4; ++mt)
#pragma unroll
      for (int r = 0; r < 4; ++r) {
        int oc = mt * 16 + quad * 4 + r;
        OUT[(b * HWN + hw) * CQ + oc] = (_Float16)(a[mt][r] + BI[oc]);
      }
  }
}

// ---------------------------------------------------------------- attn ----
// Hybrid: S computed TRANSPOSED (A=K,B=Q) so each lane holds 4 consecutive
// keys for q=l15 -> exp in regs, pack -> ONE ds_write_b64 per (i,nt).
// P[q][key] in LDS (double-buffered) -> ds_read_b128 A-frags for K=32 bf16
// PV MFMAs (16B V loads). Explicit 2-stage pipeline: iter t does
// loadV(t-1), loadK(t+1), S(t)+writeP(t), PV(t-1). psum per-lane, no
// per-body shuffles. Block = 32q, wave = 1024-key quarter; grid 1024.
__global__ __launch_bounds__(256) void attn_kernel(
    const _Float16* __restrict__ qbuf, const _Float16* __restrict__ klbuf,
    const _Float16* __restrict__ kfbuf, const short* __restrict__ vbuf,
    _Float16* __restrict__ fused) {
  const int tid  = threadIdx.x;
  const int kh   = tid >> 6;                // key quarter
  const int lane = tid & 63;
  const int quad = lane >> 4;
  const int l15  = lane & 15;
  const int bx   = blockIdx.x;
  const int pair = bx & 1;
  const int b    = (bx >> 1) & 3;
  const int qt   = (bx >> 3) << 5;          // 32 queries per block

  const _Float16* K = (pair ? kfbuf : klbuf) + b * HWN * CQ;  // [key][c] f16
  const short*    V = vbuf + b * CQ * HWN;                     // [c][key] bf16

  // Plds[wave][buf][i][q=16][72] shorts = 36864 B; combine buffer aliased.
  __shared__ __align__(16) char smem[36864];
  auto Plds = reinterpret_cast<short (*)[2][2][16][72]>(smem);
  auto Cbuf = reinterpret_cast<float (*)[64][34]>(smem);       // [3][64][34]

  // B-operand Q frags: B[k=c][n=q].
  f16x8 qfrag[2][2];
#pragma unroll
  for (int i = 0; i < 2; ++i)
#pragma unroll
    for (int kk = 0; kk < 2; ++kk)
#pragma unroll
      for (int j = 0; j < 8; ++j)
        qfrag[i][kk][j] = qbuf[(b * CQ + kk * 32 + quad * 8 + j) * HWN + qt + i * 16 + l15];

  f32x4 Oacc[2][4] = {};       // [i][ct]: row=q(quad*4+r), col=c4(ct*16+l15)
  float psum[2] = {0.f, 0.f};  // per-lane partials (q=l15, this quad's keys)

  const int kt0 = kh << 10;    // 16 tiles of 64 keys

  f16x8  kA[4][2], kB[4][2];
  bf16x8 vf[4][2];

  auto loadK = [&](f16x8 (&dst)[4][2], int KT) {
#pragma unroll
    for (int nt = 0; nt < 4; ++nt)
#pragma unroll
      for (int kk = 0; kk < 2; ++kk)
        dst[nt][kk] = *(const f16x8*)(K + (KT + nt * 16 + l15) * CQ + kk * 32 + quad * 8);
  };
  auto loadV = [&](int KT) {
#pragma unroll
    for (int ct = 0; ct < 4; ++ct)
#pragma unroll
      for (int kk = 0; kk < 2; ++kk)
        vf[ct][kk] = *(const bf16x8*)(V + (ct * 16 + l15) * HWN + KT + kk * 32 + quad * 8);
  };
  auto stageS = [&](f16x8 (&KF)[4][2], int buf) {
    f32x4 ST[2][4] = {};
#pragma unroll
    for (int i = 0; i < 2; ++i)
#pragma unroll
      for (int nt = 0; nt < 4; ++nt)
#pragma unroll
        for (int kk = 0; kk < 2; ++kk)
          ST[i][nt] = __builtin_amdgcn_mfma_f32_16x16x32_f16(KF[nt][kk], qfrag[i][kk], ST[i][nt], 0, 0, 0);
#pragma unroll
    for (int i = 0; i < 2; ++i)
#pragma unroll
      for (int nt = 0; nt < 4; ++nt) {
        bf16x4 pf;
#pragma unroll
        for (int r = 0; r < 4; ++r) {
          float p = __builtin_amdgcn_exp2f(ST[i][nt][r] - C2OFF);
          psum[i] += p;
          pf[r] = f2bf(p);
        }
        *(bf16x4*)&Plds[kh][buf][i][l15][nt * 16 + quad * 4] = pf;  // b64
      }
  };
  auto stagePV = [&](int buf) {
#pragma unroll
    for (int i = 0; i < 2; ++i)
#pragma unroll
      for (int kk = 0; kk < 2; ++kk) {
        bf16x8 pfrag = *(const bf16x8*)&Plds[kh][buf][i][l15][kk * 32 + quad * 8];  // b128
#pragma unroll
        for (int ct = 0; ct < 4; ++ct)
          Oacc[i][ct] = __builtin_amdgcn_mfma_f32_16x16x32_bf16(pfrag, vf[ct][kk], Oacc[i][ct], 0, 0, 0);
      }
  };

  loadK(kA, kt0);
  loadK(kB, kt0 + 64);
  stageS(kA, 0);                               // P(0) -> buf0
#pragma unroll
  for (int t = 1; t < 16; ++t) {
    loadV(kt0 + (t - 1) * 64);                 // V(t-1), used below
    if (t + 1 < 16) {
      if (t & 1) loadK(kA, kt0 + (t + 1) * 64);
      else       loadK(kB, kt0 + (t + 1) * 64);
    }
    if (t & 1) stageS(kB, 1); else stageS(kA, 0);   // P(t) -> buf[t&1]
    stagePV((t - 1) & 1);                      // O += P(t-1) V(t-1)
  }
  loadV(kt0 + 15 * 64);
  stagePV(1);

  // psum: reduce across quads -> every lane holds full row-sum for q=l15.
#pragma unroll
  for (int i = 0; i < 2; ++i) {
    psum[i] += __shfl_xor(psum[i], 16);
    psum[i] += __shfl_xor(psum[i], 32);
  }

  __syncthreads();   // all Plds reads done before Cbuf overwrites smem
  if (kh > 0) {
    float* dst = Cbuf[kh - 1][lane];
#pragma unroll
    for (int i = 0; i < 2; ++i)
#pragma unroll
      for (int ct = 0; ct < 4; ++ct)
#pragma unroll
        for (int r = 0; r < 4; ++r) dst[i * 16 + ct * 4 + r] = Oacc[i][ct][r];
    dst[32] = psum[0]; dst[33] = psum[1];
  }
  __syncthreads();
  if (kh == 0) {
    float ltot[2] = {psum[0], psum[1]};
#pragma unroll
    for (int k = 0; k < 3; ++k) {
      const float* src = Cbuf[k][lane];
#pragma unroll
      for (int i = 0; i < 2; ++i)
#pragma unroll
        for (int ct = 0; ct < 4; ++ct)
#pragma unroll
          for (int r = 0; r < 4; ++r) Oacc[i][ct][r] += src[i * 16 + ct * 4 + r];
      ltot[0] += src[32]; ltot[1] += src[33];
    }
#pragma unroll
    for (int i = 0; i < 2; ++i)
#pragma unroll
      for (int r = 0; r < 4; ++r) {
        float lt = __shfl(ltot[i], quad * 4 + r);   // row-sum lives at lane q
        float invl = __builtin_amdgcn_rcpf(lt);
        int qi = qt + i * 16 + quad * 4 + r;
#pragma unroll
        for (int ct = 0; ct < 4; ++ct)
          fused[(b * HWN + qi) * 128 + pair * 64 + ct * 16 + l15] =
              (_Float16)(Oacc[i][ct][r] * invl);
      }
  }
}

// ---------------------------------------------------------------- fire ----
// Wave = 16 hw x 64 oc; grid 1024; cur residual prefetched before MFMAs.
__global__ __launch_bounds__(256) void fire_kernel(
    const _Float16* __restrict__ fused, const _Float16* __restrict__ wf,
    const float* __restrict__ scale, const float* __restrict__ shift,
    const float* __restrict__ cur, float* __restrict__ out) {
  const int tid  = threadIdx.x;
  const int w    = tid >> 6;
  const int lane = tid & 63;
  const int quad = lane >> 4;
  const int l15  = lane & 15;
  const int g    = blockIdx.x & 3;
  const int bb   = blockIdx.x >> 2;
  const int b    = bb >> 6;
  const int hwt  = (bb & 63) << 6;
  const int hwb  = hwt + w * 16;

  float curv[4][4];
#pragma unroll
  for (int mt = 0; mt < 4; ++mt)
#pragma unroll
    for (int r = 0; r < 4; ++r)
      curv[mt][r] = cur[(b * CIN + g * 64 + mt * 16 + quad * 4 + r) * HWN + hwb + l15];

  f16x8 bfr[4];
#pragma unroll
  for (int k0 = 0; k0 < 4; ++k0)
    bfr[k0] = *(const f16x8*)(fused + (b * HWN + hwb + l15) * 128 + k0 * 32 + quad * 8);

  f32x4 acc[4] = {};
#pragma unroll
  for (int k0 = 0; k0 < 4; ++k0)
#pragma unroll
    for (int mt = 0; mt < 4; ++mt) {
      f16x8 af = *(const f16x8*)(wf + (g * 64 + mt * 16 + l15) * 128 + k0 * 32 + quad * 8);
      acc[mt] = __builtin_amdgcn_mfma_f32_16x16x32_f16(af, bfr[k0], acc[mt], 0, 0, 0);
    }

#pragma unroll
  for (int mt = 0; mt < 4; ++mt)
#pragma unroll
    for (int r = 0; r < 4; ++r) {
      int oc = g * 64 + mt * 16 + quad * 4 + r;
      int idx = (b * CIN + oc) * HWN + hwb + l15;
      float y = curv[mt][r] + acc[mt][r] * scale[oc] + shift[oc];
      out[idx] = fmaxf(y, 0.f);
    }
}

// -------------------------------------------------------------- launch ----
extern "C" void kernel_launch(void* const* d_in, const int* in_sizes, int n_in,
                              void* d_out, int out_size, void* d_ws, size_t ws_size,
                              hipStream_t stream) {
  const float* last  = (const float*)d_in[0];
  const float* cur   = (const float*)d_in[1];
  const float* fut   = (const float*)d_in[2];
  const float* Wqk   = (const float*)d_in[3];
  const float* bqk   = (const float*)d_in[4];
  const float* Wkl   = (const float*)d_in[5];
  const float* bkl   = (const float*)d_in[6];
  const float* Wkf   = (const float*)d_in[7];
  const float* bkf   = (const float*)d_in[8];
  const float* Wv    = (const float*)d_in[9];
  const float* bv    = (const float*)d_in[10];
  const float* Wfire = (const float*)d_in[11];
  const float* bfire = (const float*)d_in[12];
  const float* gamma = (const float*)d_in[13];
  const float* beta  = (const float*)d_in[14];
  const float* mean  = (const float*)d_in[15];
  const float* var   = (const float*)d_in[16];

  char* ws = (char*)d_ws;
  _Float16* qb     = (_Float16*)(ws);                    // [4][64][4096]  2 MB
  _Float16* klb    = (_Float16*)(ws + (2u << 20));       // [4][4096][64]  2 MB
  _Float16* kfb    = (_Float16*)(ws + (4u << 20));       // [4][4096][64]  2 MB
  short*    vb     = (short*)   (ws + (6u << 20));       // [4][64][4096]  2 MB bf16
  _Float16* fusedb = (_Float16*)(ws + (8u << 20));       // [4][4096][128] 4 MB
  char* wsm = ws + (12u << 20);
  _Float16* wqk_h = (_Float16*)(wsm);
  _Float16* wkl_h = (_Float16*)(wsm + (32u << 10));
  _Float16* wkf_h = (_Float16*)(wsm + (64u << 10));
  _Float16* wv_h  = (_Float16*)(wsm + (96u << 10));
  _Float16* wf_h  = (_Float16*)(wsm + (128u << 10));
  float*    scale = (float*)   (wsm + (192u << 10));
  float*    shift = (float*)   (wsm + (193u << 10));
  float*    out   = (float*)d_out;

  prep_kernel<<<128, 256, 0, stream>>>(Wqk, Wkl, Wkf, Wv, Wfire, bfire,
                                       gamma, beta, mean, var,
                                       wqk_h, wkl_h, wkf_h, wv_h, wf_h, scale, shift);
  proj_kernel<<<768, 256, 0, stream>>>(cur, last, fut, wqk_h, bqk, wkl_h, bkl,
                                       wkf_h, bkf, wv_h, bv, qb, klb, kfb, vb);
  attn_kernel<<<1024, 256, 0, stream>>>(qb, klb, kfb, vb, fusedb);
  fire_kernel<<<1024, 256, 0, stream>>>(fusedb, wf_h, scale, shift, cur, out);
}